// Round 11
// baseline (182.934 us; speedup 1.0000x reference)
//
#include <hip/hip_runtime.h>
#include <hip/hip_bf16.h>
#include <stdint.h>

// KipfMLPGNN: B=32, N=64 nodes, D=128, H=256, L=3 layers.
// Factorizations:
//  - First MLP layer split into per-node sender/receiver halves (k_T, fp16).
//  - Arc blend: agg = Sum_c (1-a)*m0 + Sum_c a*m1 -> phase in grid.z,
//    partials combined by f32 atomicAdd (threshold 55.68 >> LSB noise).
// k_edge v11: r in the MFMA M-dimension. Per c: A(r,k)=relu(Ts(c,k)+Tr(r,k))
// built in registers (Tr frags hoisted, c-invariant; Ts lane-broadcast),
// B = hoisted W2 frags. C rows = r -> weighted c-sum accumulates IN REGISTERS
// (Sacc[nt][j]). Zero LDS, zero per-r barriers, no h materialization.
// Block=(b,16r), 4 waves x 32d; grid.z = phase x c-half; arcs pre-transposed.

#define NB 32
#define NN 64
#define DD 128
#define HH 256

typedef __attribute__((ext_vector_type(4))) float f32x4;
typedef __attribute__((ext_vector_type(8))) _Float16 f16x8;

__device__ __forceinline__ uint64_t cvt4h(f32x4 v) {
  union { _Float16 h[4]; uint64_t u; } x;
  x.h[0] = (_Float16)v[0]; x.h[1] = (_Float16)v[1];
  x.h[2] = (_Float16)v[2]; x.h[3] = (_Float16)v[3];
  return x.u;
}

// E[node][d] = table[x[node]][d]  (2048 x 128 f32)
__global__ __launch_bounds__(256) void k_gather(const int* __restrict__ x,
                                                const float* __restrict__ table,
                                                float* __restrict__ E) {
  int i = blockIdx.x * 256 + threadIdx.x;
  int node = i >> 5;
  ((f32x4*)E)[i] = ((const f32x4*)table)[(size_t)x[node] * 32 + (i & 31)];
}

// W1fp[2][256h][256in] fp16 (natural layout), W2fp[2][128d][256h] fp16.
__global__ __launch_bounds__(256) void k_prep(const float* __restrict__ W1_0,
                                              const float* __restrict__ W1_1,
                                              const float* __restrict__ W2_0,
                                              const float* __restrict__ W2_1,
                                              _Float16* __restrict__ W1fp,
                                              _Float16* __restrict__ W2fp) {
  int tid = blockIdx.x * 256 + threadIdx.x;   // 192*256 = 49152 f32x4 chunks
  const float* src; uint64_t* dst; int off;
  if (tid < 32768) {
    src = (tid < 16384) ? W1_0 : W1_1;
    off = tid & 16383;
    dst = (uint64_t*)W1fp + (tid >> 14) * 16384 + off;
  } else {
    int t2 = tid - 32768;
    src = (t2 < 8192) ? W2_0 : W2_1;
    off = t2 & 8191;
    dst = (uint64_t*)W2fp + (t2 >> 13) * 8192 + off;
  }
  *dst = cvt4h(((const f32x4*)src)[off]);
}

// arcsT[b][c][r] = arcs[b][r][c]   (coalesced read, scattered write)
__global__ __launch_bounds__(256) void k_arcT(const int* __restrict__ arcs,
                                              int* __restrict__ arcsT) {
  int i = blockIdx.x * 256 + threadIdx.x;      // 131072
  int b = i >> 12, rc = i & 4095, r = rc >> 6, c = rc & 63;
  arcsT[b * 4096 + c * 64 + r] = arcs[i];
}

// Tfp[node][1024] = [Ts0 | Tr0+b1_0 | Ts1 | Tr1+b1_1]  (fp16)
// grid (8, 32): x = q*2+half (q in {Ts0,Tr0,Ts1,Tr1}, 128 h-cols), y = 64-node blk
__global__ __launch_bounds__(256) void k_T(const float* __restrict__ E,
                                           const _Float16* __restrict__ W1fp,
                                           const float* __restrict__ b1_0,
                                           const float* __restrict__ b1_1,
                                           _Float16* __restrict__ Tfp) {
  __shared__ char Els[64 * 256];     // 64 nodes x 128 f16, swizzled rows (256B)
  int t = threadIdx.x;
  int gi = blockIdx.x;
  int q = gi >> 1;                   // group 0..3
  int hb = (gi & 1) * 128;           // h-half
  int inoff = (q & 1) * 128;         // sender(0) / receiver(128) input half
  int node0 = blockIdx.y * 64;

#pragma unroll
  for (int ii = 0; ii < 8; ++ii) {
    int idx = ii * 256 + t;          // f32x4 chunk: row=idx>>5, ck=idx&31
    int row = idx >> 5, ck = idx & 31;
    f32x4 v = ((const f32x4*)(E + (size_t)node0 * 128))[idx];
    *(uint64_t*)(Els + row * 256 + ((ck * 8) ^ ((row & 7) << 4))) = cvt4h(v);
  }
  __syncthreads();

  int lane = t & 63, w = t >> 6;     // 4 waves, each 64M x 32N
  int col = lane & 15, khi = lane >> 4;

  const _Float16* Wq = W1fp + (q >> 1) * 65536;
  f16x8 bfr[2][4];
#pragma unroll
  for (int nt = 0; nt < 2; ++nt) {
    int n = w * 32 + nt * 16 + col;
#pragma unroll
    for (int ks = 0; ks < 4; ++ks)
      bfr[nt][ks] = *(const f16x8*)(Wq + (hb + n) * 256 + inoff + ks * 32 + khi * 8);
  }

  f32x4 acc[4][2];
  const f32x4 z = {0.f, 0.f, 0.f, 0.f};
#pragma unroll
  for (int mt = 0; mt < 4; ++mt)
#pragma unroll
    for (int nt = 0; nt < 2; ++nt) acc[mt][nt] = z;

#pragma unroll
  for (int ks = 0; ks < 4; ++ks) {
    f16x8 a[4];
#pragma unroll
    for (int mt = 0; mt < 4; ++mt) {
      int c = mt * 16 + col;
      a[mt] = *(const f16x8*)(Els + c * 256 + ((ks * 64 + khi * 16) ^ ((c & 7) << 4)));
    }
#pragma unroll
    for (int mt = 0; mt < 4; ++mt)
#pragma unroll
      for (int nt = 0; nt < 2; ++nt)
        acc[mt][nt] = __builtin_amdgcn_mfma_f32_16x16x32_f16(a[mt], bfr[nt][ks],
                                                             acc[mt][nt], 0, 0, 0);
  }

  const float* b1q = (q >> 1) ? b1_1 : b1_0;
  float bv[2];
#pragma unroll
  for (int nt = 0; nt < 2; ++nt)
    bv[nt] = (q & 1) ? b1q[hb + w * 32 + nt * 16 + col] : 0.f;

#pragma unroll
  for (int mt = 0; mt < 4; ++mt)
#pragma unroll
    for (int nt = 0; nt < 2; ++nt)
#pragma unroll
      for (int j = 0; j < 4; ++j) {
        int node = node0 + mt * 16 + khi * 4 + j;
        int cgl = q * 256 + hb + w * 32 + nt * 16 + col;
        Tfp[(size_t)node * 1024 + cgl] = (_Float16)(acc[mt][nt][j] + bv[nt]);
      }
}

// out[b][d] = E[b][0][d]  (initializes d_out deterministically each call)
__global__ __launch_bounds__(256) void k_init(const float* __restrict__ E,
                                              float* __restrict__ out) {
  int i = blockIdx.x * 256 + threadIdx.x;      // 4096
  out[i] = E[(size_t)(i >> 7) * (NN * DD) + (i & 127)];
}

// k_edge v11: grid (rb, 32, 4). z: p = z>>1 (phase), ch = z&1 (c-half).
// Block = (b, 16 r's), 256 thr / 4 waves; wave w owns d-cols [w*32,w*32+32).
// A-frag rows = r (Tr hoisted), B = W2 frags (hoisted). Per c: build A in
// regs, 16 MFMA, weight by arcsT, accumulate Sacc in regs. atomicAdd out.
template <int LAST>
__global__ __launch_bounds__(256) void k_edge(const _Float16* __restrict__ Tfp,
                                              const int* __restrict__ arcsT,
                                              float* __restrict__ Eout,
                                              const _Float16* __restrict__ W2fp,
                                              const float* __restrict__ b2_0,
                                              const float* __restrict__ b2_1) {
  int t = threadIdx.x;
  int z = blockIdx.z;
  int p = z >> 1, ch = z & 1;
  int b = blockIdx.y;
  int rbase = LAST ? 0 : blockIdx.x * 16;
  int lane = t & 63, w = t >> 6;
  int col = lane & 15, khi = lane >> 4;

  const _Float16* Tb = Tfp + (size_t)b * NN * 1024;

  // hoist Tr fragments: Tr(rbase+col, ks*32 + khi*8 + ..)   (32 VGPR)
  f16x8 tr[8];
  {
    const _Float16* trp = Tb + (rbase + col) * 1024 + p * 512 + 256 + khi * 8;
#pragma unroll
    for (int ks = 0; ks < 8; ++ks)
      tr[ks] = *(const f16x8*)(trp + ks * 32);
  }
  // hoist W2 fragments for this wave's 32 d-cols   (64 VGPR)
  const _Float16* W2p = W2fp + p * 32768;
  f16x8 bv[2][8];
#pragma unroll
  for (int nt = 0; nt < 2; ++nt) {
    int d = w * 32 + nt * 16 + col;
#pragma unroll
    for (int ks = 0; ks < 8; ++ks)
      bv[nt][ks] = *(const f16x8*)(W2p + d * 256 + ks * 32 + khi * 8);
  }
  const float* b2p = p ? b2_1 : b2_0;
  float b2v[2] = {b2p[w * 32 + col], b2p[w * 32 + 16 + col]};

  f32x4 Sacc[2];
  const f32x4 z4 = {0.f, 0.f, 0.f, 0.f};
  Sacc[0] = z4; Sacc[1] = z4;

  const int* aT = arcsT + (size_t)b * 4096 + rbase + khi * 4;

#pragma unroll 2
  for (int ci = 0; ci < 32; ++ci) {
    int c = ch * 32 + ci;
    const _Float16* tsp = Tb + c * 1024 + p * 512 + khi * 8;
    f32x4 acc0 = z4, acc1 = z4;
#pragma unroll
    for (int ks = 0; ks < 8; ++ks) {
      f16x8 ts = *(const f16x8*)(tsp + ks * 32);   // broadcast within khi grp
      f16x8 zv = {};
      f16x8 a = __builtin_elementwise_max(ts + tr[ks], zv);
      acc0 = __builtin_amdgcn_mfma_f32_16x16x32_f16(a, bv[0][ks], acc0, 0, 0, 0);
      acc1 = __builtin_amdgcn_mfma_f32_16x16x32_f16(a, bv[1][ks], acc1, 0, 0, 0);
    }
    const int4 av = *(const int4*)(aT + c * 64);
#pragma unroll
    for (int j = 0; j < 4; ++j) {
      int ai = (j == 0) ? av.x : (j == 1) ? av.y : (j == 2) ? av.z : av.w;
      float wgt = p ? (float)ai : 1.0f - (float)ai;
      Sacc[0][j] = fmaf(wgt, fmaxf(acc0[j] + b2v[0], 0.f), Sacc[0][j]);
      Sacc[1][j] = fmaf(wgt, fmaxf(acc1[j] + b2v[1], 0.f), Sacc[1][j]);
    }
  }

  // write: row r = rbase + khi*4 + j, col d = w*32 + nt*16 + col
#pragma unroll
  for (int nt = 0; nt < 2; ++nt) {
    int d = w * 32 + nt * 16 + col;
#pragma unroll
    for (int j = 0; j < 4; ++j) {
      if (LAST) {
        if (khi == 0 && j == 0)
          atomicAdd(Eout + b * DD + d, Sacc[nt][j]);
      } else {
        int r = rbase + khi * 4 + j;
        atomicAdd(Eout + ((size_t)(b * NN + r)) * DD + d, Sacc[nt][j]);
      }
    }
  }
}

extern "C" void kernel_launch(void* const* d_in, const int* in_sizes, int n_in,
                              void* d_out, int out_size, void* d_ws, size_t ws_size,
                              hipStream_t stream) {
  const int* x       = (const int*)d_in[0];
  const int* arcs    = (const int*)d_in[1];
  const float* table = (const float*)d_in[3];
  const float* W1_0  = (const float*)d_in[4];
  const float* b1_0  = (const float*)d_in[5];
  const float* W2_0  = (const float*)d_in[6];
  const float* b2_0  = (const float*)d_in[7];
  const float* W1_1  = (const float*)d_in[8];
  const float* b1_1  = (const float*)d_in[9];
  const float* W2_1  = (const float*)d_in[10];
  const float* b2_1  = (const float*)d_in[11];
  float* out = (float*)d_out;

  char* ws = (char*)d_ws;
  float* E         = (float*)ws;                      // 1 MB
  _Float16* Tfp    = (_Float16*)(ws + (1u << 20));    // 4 MB
  _Float16* W1fp   = (_Float16*)(ws + (5u << 20));    // 256 KB
  _Float16* W2fp   = (_Float16*)(ws + (5u << 20) + (256u << 10));  // 128 KB
  int* arcsT       = (int*)(ws + (5u << 20) + (384u << 10));       // 512 KB

  k_gather<<<256, 256, 0, stream>>>(x, table, E);
  k_prep<<<192, 256, 0, stream>>>(W1_0, W1_1, W2_0, W2_1, W1fp, W2fp);
  k_arcT<<<512, 256, 0, stream>>>(arcs, arcsT);
  for (int l = 0; l < 3; ++l) {
    k_T<<<dim3(8, 32), 256, 0, stream>>>(E, W1fp, b1_0, b1_1, Tfp);
    if (l == 2) {
      k_init<<<16, 256, 0, stream>>>(E, out);
      k_edge<1><<<dim3(1, 32, 4), 256, 0, stream>>>(Tfp, arcsT, out,
                                                    W2fp, b2_0, b2_1);
    } else {
      k_edge<0><<<dim3(4, 32, 4), 256, 0, stream>>>(Tfp, arcsT, E,
                                                    W2fp, b2_0, b2_1);
    }
  }
}

// Round 12
// 129.182 us; speedup vs baseline: 1.4161x; 1.4161x over previous
//
#include <hip/hip_runtime.h>
#include <hip/hip_bf16.h>
#include <stdint.h>

// KipfMLPGNN: B=32, N=64 nodes, D=128, H=256, L=3 layers.
// Factorizations:
//  - First MLP layer split into per-node sender/receiver halves (k_T, fp16).
//  - Arc blend: agg = Sum_c (1-a)*m0 + Sum_c a*m1 -> phase in grid.z.
// k_edge v12: r in MFMA M-dim (v11) + (1) z = p x c-quarter -> 1024 blocks
// (4/CU, was 2/CU grid-limited at 19% occ), (2) 4 independent MFMA chains
// (ks split in halves, depth 4) to cover dependent-MFMA latency, (3) NO
// atomics: per-slice partial buffers Sp[z] (plain stores; atomicAdd was
// bouncing E lines between XCDs 4-way), folded by k_sum: E += sum_z Sp[z].

#define NB 32
#define NN 64
#define DD 128
#define HH 256

typedef __attribute__((ext_vector_type(4))) float f32x4;
typedef __attribute__((ext_vector_type(8))) _Float16 f16x8;

__device__ __forceinline__ uint64_t cvt4h(f32x4 v) {
  union { _Float16 h[4]; uint64_t u; } x;
  x.h[0] = (_Float16)v[0]; x.h[1] = (_Float16)v[1];
  x.h[2] = (_Float16)v[2]; x.h[3] = (_Float16)v[3];
  return x.u;
}

// E[node][d] = table[x[node]][d]  (2048 x 128 f32)
__global__ __launch_bounds__(256) void k_gather(const int* __restrict__ x,
                                                const float* __restrict__ table,
                                                float* __restrict__ E) {
  int i = blockIdx.x * 256 + threadIdx.x;
  int node = i >> 5;
  ((f32x4*)E)[i] = ((const f32x4*)table)[(size_t)x[node] * 32 + (i & 31)];
}

// W1fp[2][256h][256in] fp16 (natural layout), W2fp[2][128d][256h] fp16.
__global__ __launch_bounds__(256) void k_prep(const float* __restrict__ W1_0,
                                              const float* __restrict__ W1_1,
                                              const float* __restrict__ W2_0,
                                              const float* __restrict__ W2_1,
                                              _Float16* __restrict__ W1fp,
                                              _Float16* __restrict__ W2fp) {
  int tid = blockIdx.x * 256 + threadIdx.x;   // 192*256 = 49152 f32x4 chunks
  const float* src; uint64_t* dst; int off;
  if (tid < 32768) {
    src = (tid < 16384) ? W1_0 : W1_1;
    off = tid & 16383;
    dst = (uint64_t*)W1fp + (tid >> 14) * 16384 + off;
  } else {
    int t2 = tid - 32768;
    src = (t2 < 8192) ? W2_0 : W2_1;
    off = t2 & 8191;
    dst = (uint64_t*)W2fp + (t2 >> 13) * 8192 + off;
  }
  *dst = cvt4h(((const f32x4*)src)[off]);
}

// arcsT[b][c][r] = arcs[b][r][c]
__global__ __launch_bounds__(256) void k_arcT(const int* __restrict__ arcs,
                                              int* __restrict__ arcsT) {
  int i = blockIdx.x * 256 + threadIdx.x;      // 131072
  int b = i >> 12, rc = i & 4095, r = rc >> 6, c = rc & 63;
  arcsT[b * 4096 + c * 64 + r] = arcs[i];
}

// Tfp[node][1024] = [Ts0 | Tr0+b1_0 | Ts1 | Tr1+b1_1]  (fp16)
// grid (8, 64): x = q*2+half, y = 32-node block.
__global__ __launch_bounds__(256) void k_T(const float* __restrict__ E,
                                           const _Float16* __restrict__ W1fp,
                                           const float* __restrict__ b1_0,
                                           const float* __restrict__ b1_1,
                                           _Float16* __restrict__ Tfp) {
  __shared__ char Els[32 * 256];     // 32 nodes x 128 f16, swizzled rows
  int t = threadIdx.x;
  int gi = blockIdx.x;
  int q = gi >> 1;                   // group 0..3
  int hb = (gi & 1) * 128;           // h-half
  int inoff = (q & 1) * 128;         // sender(0) / receiver(128) input half
  int node0 = blockIdx.y * 32;

#pragma unroll
  for (int ii = 0; ii < 4; ++ii) {
    int idx = ii * 256 + t;          // f32x4 chunk: row=idx>>5, ck=idx&31
    int row = idx >> 5, ck = idx & 31;
    f32x4 v = ((const f32x4*)(E + (size_t)node0 * 128))[idx];
    *(uint64_t*)(Els + row * 256 + ((ck * 8) ^ ((row & 7) << 4))) = cvt4h(v);
  }
  __syncthreads();

  int lane = t & 63, w = t >> 6;     // 4 waves, each 32M x 32N
  int col = lane & 15, khi = lane >> 4;

  const _Float16* Wq = W1fp + (q >> 1) * 65536;
  f16x8 bfr[2][4];
#pragma unroll
  for (int nt = 0; nt < 2; ++nt) {
    int n = w * 32 + nt * 16 + col;
#pragma unroll
    for (int ks = 0; ks < 4; ++ks)
      bfr[nt][ks] = *(const f16x8*)(Wq + (hb + n) * 256 + inoff + ks * 32 + khi * 8);
  }

  f32x4 acc[2][2];
  const f32x4 z = {0.f, 0.f, 0.f, 0.f};
#pragma unroll
  for (int mt = 0; mt < 2; ++mt) { acc[mt][0] = z; acc[mt][1] = z; }

#pragma unroll
  for (int ks = 0; ks < 4; ++ks) {
    f16x8 a[2];
#pragma unroll
    for (int mt = 0; mt < 2; ++mt) {
      int c = mt * 16 + col;
      a[mt] = *(const f16x8*)(Els + c * 256 + ((ks * 64 + khi * 16) ^ ((c & 7) << 4)));
    }
#pragma unroll
    for (int mt = 0; mt < 2; ++mt)
#pragma unroll
      for (int nt = 0; nt < 2; ++nt)
        acc[mt][nt] = __builtin_amdgcn_mfma_f32_16x16x32_f16(a[mt], bfr[nt][ks],
                                                             acc[mt][nt], 0, 0, 0);
  }

  const float* b1q = (q >> 1) ? b1_1 : b1_0;
  float bv[2];
#pragma unroll
  for (int nt = 0; nt < 2; ++nt)
    bv[nt] = (q & 1) ? b1q[hb + w * 32 + nt * 16 + col] : 0.f;

#pragma unroll
  for (int mt = 0; mt < 2; ++mt)
#pragma unroll
    for (int nt = 0; nt < 2; ++nt)
#pragma unroll
      for (int j = 0; j < 4; ++j) {
        int node = node0 + mt * 16 + khi * 4 + j;
        int cgl = q * 256 + hb + w * 32 + nt * 16 + col;
        Tfp[(size_t)node * 1024 + cgl] = (_Float16)(acc[mt][nt][j] + bv[nt]);
      }
}

// E += sum_z Sp[z]   (262144 f32 = 65536 f32x4)
__global__ __launch_bounds__(256) void k_sum(float* __restrict__ E,
                                             const float* __restrict__ Sp) {
  int i = blockIdx.x * 256 + threadIdx.x;      // 65536 f32x4 chunks
  f32x4 acc = ((const f32x4*)E)[i];
#pragma unroll
  for (int zz = 0; zz < 8; ++zz)
    acc += ((const f32x4*)Sp)[zz * 65536 + i];
  ((f32x4*)E)[i] = acc;
}

// out[b][d] = E[b][0][d] + sum_z SpL[z][b][d]
__global__ __launch_bounds__(256) void k_out(const float* __restrict__ E,
                                             const float* __restrict__ SpL,
                                             float* __restrict__ out) {
  int i = blockIdx.x * 256 + threadIdx.x;      // 4096
  float acc = E[(size_t)(i >> 7) * (NN * DD) + (i & 127)];
#pragma unroll
  for (int zz = 0; zz < 8; ++zz)
    acc += SpL[zz * 4096 + i];
  out[i] = acc;
}

// k_edge v12: grid (rb, 32, 8). z: p = z>>2 (phase), cq = z&3 (c-quarter).
// Block = (b, 16 r's), 256 thr / 4 waves; wave w owns d-cols [w*32,w*32+32).
// Per c (16 of them): A(r,k)=relu(Ts(c,k)+Tr(r,k)) in regs, 4 MFMA chains
// depth 4, blend by arcsT, accumulate Sacc. Plain stores to Sp[z] partials.
template <int LAST>
__global__ __launch_bounds__(256) void k_edge(const _Float16* __restrict__ Tfp,
                                              const int* __restrict__ arcsT,
                                              float* __restrict__ Sp,
                                              const _Float16* __restrict__ W2fp,
                                              const float* __restrict__ b2_0,
                                              const float* __restrict__ b2_1) {
  int t = threadIdx.x;
  int z = blockIdx.z;
  int p = z >> 2, cq = z & 3;
  int b = blockIdx.y;
  int rbase = LAST ? 0 : blockIdx.x * 16;
  int lane = t & 63, w = t >> 6;
  int col = lane & 15, khi = lane >> 4;

  const _Float16* Tb = Tfp + (size_t)b * NN * 1024;

  // hoist Tr fragments (32 VGPR)
  f16x8 tr[8];
  {
    const _Float16* trp = Tb + (rbase + col) * 1024 + p * 512 + 256 + khi * 8;
#pragma unroll
    for (int ks = 0; ks < 8; ++ks)
      tr[ks] = *(const f16x8*)(trp + ks * 32);
  }
  // hoist W2 fragments for this wave's 32 d-cols (64 VGPR)
  const _Float16* W2p = W2fp + p * 32768;
  f16x8 bv[2][8];
#pragma unroll
  for (int nt = 0; nt < 2; ++nt) {
    int d = w * 32 + nt * 16 + col;
#pragma unroll
    for (int ks = 0; ks < 8; ++ks)
      bv[nt][ks] = *(const f16x8*)(W2p + d * 256 + ks * 32 + khi * 8);
  }
  const float* b2p = p ? b2_1 : b2_0;
  float b2v[2] = {b2p[w * 32 + col], b2p[w * 32 + 16 + col]};

  f32x4 Sacc[2];
  const f32x4 z4 = {0.f, 0.f, 0.f, 0.f};
  Sacc[0] = z4; Sacc[1] = z4;

  const int* aT = arcsT + (size_t)b * 4096 + rbase + khi * 4;

#pragma unroll 1
  for (int ci = 0; ci < 16; ++ci) {
    int c = cq * 16 + ci;
    const _Float16* tsp = Tb + c * 1024 + p * 512 + khi * 8;
    f16x8 ts[8];
#pragma unroll
    for (int ks = 0; ks < 8; ++ks)
      ts[ks] = *(const f16x8*)(tsp + ks * 32);   // broadcast within khi grp

    f32x4 a0a = z4, a0b = z4, a1a = z4, a1b = z4;   // 4 chains, depth 4
#pragma unroll
    for (int ks = 0; ks < 4; ++ks) {
      f16x8 zv = {};
      f16x8 aA = __builtin_elementwise_max(ts[ks] + tr[ks], zv);
      f16x8 aB = __builtin_elementwise_max(ts[ks + 4] + tr[ks + 4], zv);
      a0a = __builtin_amdgcn_mfma_f32_16x16x32_f16(aA, bv[0][ks], a0a, 0, 0, 0);
      a0b = __builtin_amdgcn_mfma_f32_16x16x32_f16(aB, bv[0][ks + 4], a0b, 0, 0, 0);
      a1a = __builtin_amdgcn_mfma_f32_16x16x32_f16(aA, bv[1][ks], a1a, 0, 0, 0);
      a1b = __builtin_amdgcn_mfma_f32_16x16x32_f16(aB, bv[1][ks + 4], a1b, 0, 0, 0);
    }
    f32x4 acc0 = a0a + a0b;
    f32x4 acc1 = a1a + a1b;

    const int4 av = *(const int4*)(aT + c * 64);
#pragma unroll
    for (int j = 0; j < 4; ++j) {
      int ai = (j == 0) ? av.x : (j == 1) ? av.y : (j == 2) ? av.z : av.w;
      float wgt = p ? (float)ai : 1.0f - (float)ai;
      Sacc[0][j] = fmaf(wgt, fmaxf(acc0[j] + b2v[0], 0.f), Sacc[0][j]);
      Sacc[1][j] = fmaf(wgt, fmaxf(acc1[j] + b2v[1], 0.f), Sacc[1][j]);
    }
  }

  // store partials: slice z, row r = rbase+khi*4+j, col d = w*32+nt*16+col
  if (LAST) {
    if (khi == 0) {
#pragma unroll
      for (int nt = 0; nt < 2; ++nt) {
        int d = w * 32 + nt * 16 + col;
        Sp[(size_t)z * (NB * DD) + b * DD + d] = Sacc[nt][0];
      }
    }
  } else {
    float* Spz = Sp + (size_t)z * (NB * NN * DD);
#pragma unroll
    for (int nt = 0; nt < 2; ++nt) {
      int d = w * 32 + nt * 16 + col;
#pragma unroll
      for (int j = 0; j < 4; ++j) {
        int r = rbase + khi * 4 + j;
        Spz[((size_t)b * NN + r) * DD + d] = Sacc[nt][j];
      }
    }
  }
}

extern "C" void kernel_launch(void* const* d_in, const int* in_sizes, int n_in,
                              void* d_out, int out_size, void* d_ws, size_t ws_size,
                              hipStream_t stream) {
  const int* x       = (const int*)d_in[0];
  const int* arcs    = (const int*)d_in[1];
  const float* table = (const float*)d_in[3];
  const float* W1_0  = (const float*)d_in[4];
  const float* b1_0  = (const float*)d_in[5];
  const float* W2_0  = (const float*)d_in[6];
  const float* b2_0  = (const float*)d_in[7];
  const float* W1_1  = (const float*)d_in[8];
  const float* b1_1  = (const float*)d_in[9];
  const float* W2_1  = (const float*)d_in[10];
  const float* b2_1  = (const float*)d_in[11];
  float* out = (float*)d_out;

  char* ws = (char*)d_ws;
  float* E         = (float*)ws;                                   // 1 MB
  _Float16* Tfp    = (_Float16*)(ws + (1u << 20));                 // 4 MB
  _Float16* W1fp   = (_Float16*)(ws + (5u << 20));                 // 256 KB
  _Float16* W2fp   = (_Float16*)(ws + (5u << 20) + (256u << 10));  // 128 KB
  int* arcsT       = (int*)(ws + (5u << 20) + (384u << 10));       // 512 KB
  float* Sp        = (float*)(ws + (6u << 20));                    // 8 MB
  float* SpL       = (float*)(ws + (14u << 20));                   // 128 KB

  k_gather<<<256, 256, 0, stream>>>(x, table, E);
  k_prep<<<192, 256, 0, stream>>>(W1_0, W1_1, W2_0, W2_1, W1fp, W2fp);
  k_arcT<<<512, 256, 0, stream>>>(arcs, arcsT);
  for (int l = 0; l < 3; ++l) {
    k_T<<<dim3(8, 64), 256, 0, stream>>>(E, W1fp, b1_0, b1_1, Tfp);
    if (l == 2) {
      k_edge<1><<<dim3(1, 32, 8), 256, 0, stream>>>(Tfp, arcsT, SpL,
                                                    W2fp, b2_0, b2_1);
      k_out<<<16, 256, 0, stream>>>(E, SpL, out);
    } else {
      k_edge<0><<<dim3(4, 32, 8), 256, 0, stream>>>(Tfp, arcsT, Sp,
                                                    W2fp, b2_0, b2_1);
      k_sum<<<256, 256, 0, stream>>>(E, Sp);
    }
  }
}